// Round 4
// baseline (207.650 us; speedup 1.0000x reference)
//
#include <hip/hip_runtime.h>
#include <math.h>

// CoralLossV2: mean over (B, Km1) of
//   max(x,0) - x*[t > k] + log1p(exp(-|x|))  ==  softplus(x) - x*[t > k]
// B = 524288, Km1 = 64, logits fp32, targets int32, output: 1 fp32 scalar.
//
// R3 analysis: kernel ~70 us vs ~21 us memory floor; still latency-bound.
// The grid-stride loop drains all loads each iteration (target loads issue
// last -> early vmcnt wait) and only 4 outer iterations -> pipeline never
// fills. Fix: fully unrolled flat load batch — 8 float4 + 8 targets issued
// up-front per thread (GRID=4096), compute after. kbase is thread-invariant
// across chunks (stride % 16 rows == 0), folded into c = t - kbase.

#define BLOCK 256
#define GRID 4096
#define NTHREADS (GRID * BLOCK)   // 1,048,576
#define PER_THREAD 8              // n_vec4 / NTHREADS for the fixed shape

__device__ __forceinline__ float bce4(const float4 x4, const int c) {
    const float LOG2E = 1.44269504088896f;
    const float LN2   = 0.69314718055995f;
    const float xs[4] = {x4.x, x4.y, x4.z, x4.w};
    float s = 0.0f;
    #pragma unroll
    for (int j = 0; j < 4; ++j) {
        const float x = xs[j];
        // log1p(exp(-|x|)) = ln2 * log2(1 + exp2(-|x|*log2e)) via hw trans ops
        const float e  = __builtin_amdgcn_exp2f(-fabsf(x) * LOG2E);
        const float lg = __builtin_amdgcn_logf(1.0f + e);
        // max(x,0) - x*[c > j] == (c > j) ? max(-x,0) : max(x,0); j is inline const
        const float m  = fmaxf((c > j) ? -x : x, 0.0f);
        s += fmaf(LN2, lg, m);
    }
    return s;
}

__global__ __launch_bounds__(BLOCK) void coral_loss_kernel(
    const float* __restrict__ logits,
    const int* __restrict__ targets,
    float* __restrict__ out,
    int n_vec4,        // B*Km1/4
    float inv_count)   // 1/(B*Km1)
{
    const float4* __restrict__ L4 = reinterpret_cast<const float4*>(logits);
    const int tid = blockIdx.x * BLOCK + threadIdx.x;

    float a0 = 0.0f, a1 = 0.0f, a2 = 0.0f, a3 = 0.0f;

    if (n_vec4 == NTHREADS * PER_THREAD) {
        // fast path for the fixed shape: all loads issued before any use
        const int kbase = (tid & 15) << 2;   // invariant: NTHREADS % 16 == 0
        float4 x[PER_THREAD];
        int c[PER_THREAD];
        #pragma unroll
        for (int m = 0; m < PER_THREAD; ++m)
            x[m] = L4[tid + m * NTHREADS];
        #pragma unroll
        for (int m = 0; m < PER_THREAD; ++m)
            c[m] = targets[(tid + m * NTHREADS) >> 4] - kbase;
        #pragma unroll
        for (int m = 0; m < PER_THREAD; m += 4) {
            a0 += bce4(x[m + 0], c[m + 0]);
            a1 += bce4(x[m + 1], c[m + 1]);
            a2 += bce4(x[m + 2], c[m + 2]);
            a3 += bce4(x[m + 3], c[m + 3]);
        }
    } else {
        // generic grid-stride fallback
        for (int idx = tid; idx < n_vec4; idx += NTHREADS) {
            const int kb = (idx & 15) << 2;
            a0 += bce4(L4[idx], targets[idx >> 4] - kb);
        }
    }

    float acc = ((a0 + a1) + (a2 + a3)) * inv_count;

    // wave-64 shuffle reduce
    #pragma unroll
    for (int off = 32; off > 0; off >>= 1)
        acc += __shfl_down(acc, off, 64);

    __shared__ float wave_sums[BLOCK / 64];
    const int lane = threadIdx.x & 63;
    const int wid = threadIdx.x >> 6;
    if (lane == 0) wave_sums[wid] = acc;
    __syncthreads();
    if (threadIdx.x == 0) {
        float s = 0.0f;
        #pragma unroll
        for (int w = 0; w < BLOCK / 64; ++w) s += wave_sums[w];
        atomicAdd(out, s);  // device-scope by default on CDNA
    }
}

extern "C" void kernel_launch(void* const* d_in, const int* in_sizes, int n_in,
                              void* d_out, int out_size, void* d_ws, size_t ws_size,
                              hipStream_t stream) {
    const float* logits = (const float*)d_in[0];
    const int* targets = (const int*)d_in[1];
    float* out = (float*)d_out;

    const int n_logits = in_sizes[0];       // B * Km1
    const int n_vec4 = n_logits / 4;
    const float inv_count = 1.0f / (float)n_logits;

    // d_out is poisoned to 0xAA before every timed launch -> zero it.
    hipMemsetAsync(d_out, 0, sizeof(float) * out_size, stream);

    coral_loss_kernel<<<GRID, BLOCK, 0, stream>>>(
        logits, targets, out, n_vec4, inv_count);
}

// Round 5
// 195.157 us; speedup vs baseline: 1.0640x; 1.0640x over previous
//
#include <hip/hip_runtime.h>
#include <math.h>

// CoralLossV2: mean over (B, Km1) of
//   max(x,0) - x*[t > k] + log1p(exp(-|x|))  ==  softplus(x) - x*[t > k]
// B = 524288, Km1 = 64, logits fp32, targets int32, output: 1 fp32 scalar.
//
// R4 analysis: kernel time (~70-82 us) is INSENSITIVE to load pipelining
// (R2 minimal / R3 4-in-flight / R4 16-in-flight all equal) -> not latency.
// Theory: 2048-4096 device-scope fp32 atomicAdds to ONE address serialize
// (~80 cyc each across 8 non-coherent XCD L2s) once the VALU work no longer
// staggers block completion. R1 (VALU-bound, staggered) hid the tail; R4
// (more blocks = more atomics) regressed. Fix: no atomics — per-block
// partials to d_ws, then a 1-block reduce kernel writes out[0] directly.

#define BLOCK 256
#define GRID 2048
#define STRIDE (GRID * BLOCK)

__device__ __forceinline__ float bce4(const float4 x4, const int c) {
    const float LOG2E = 1.44269504088896f;
    const float LN2   = 0.69314718055995f;
    const float xs[4] = {x4.x, x4.y, x4.z, x4.w};
    float s = 0.0f;
    #pragma unroll
    for (int j = 0; j < 4; ++j) {
        const float x = xs[j];
        // log1p(exp(-|x|)) = ln2 * log2(1 + exp2(-|x|*log2e)) via hw trans ops
        const float e  = __builtin_amdgcn_exp2f(-fabsf(x) * LOG2E);
        const float lg = __builtin_amdgcn_logf(1.0f + e);
        // max(x,0) - x*[c > j] == (c > j) ? max(-x,0) : max(x,0)
        const float m  = fmaxf((c > j) ? -x : x, 0.0f);
        s += fmaf(LN2, lg, m);
    }
    return s;
}

__device__ __forceinline__ float block_reduce(float acc, float* wave_sums) {
    #pragma unroll
    for (int off = 32; off > 0; off >>= 1)
        acc += __shfl_down(acc, off, 64);
    const int lane = threadIdx.x & 63;
    const int wid = threadIdx.x >> 6;
    if (lane == 0) wave_sums[wid] = acc;
    __syncthreads();
    float s = 0.0f;
    if (threadIdx.x == 0) {
        #pragma unroll
        for (int w = 0; w < BLOCK / 64; ++w) s += wave_sums[w];
    }
    return s;
}

__global__ __launch_bounds__(BLOCK) void coral_loss_main(
    const float* __restrict__ logits,
    const int* __restrict__ targets,
    float* __restrict__ partials,   // GRID floats in d_ws
    int n_vec4,                     // B*Km1/4
    float inv_count)                // 1/(B*Km1)
{
    const float4* __restrict__ L4 = reinterpret_cast<const float4*>(logits);
    float a0 = 0.0f, a1 = 0.0f, a2 = 0.0f, a3 = 0.0f;
    int idx = blockIdx.x * BLOCK + threadIdx.x;

    for (; idx + 3 * STRIDE < n_vec4; idx += 4 * STRIDE) {
        const int i0 = idx, i1 = idx + STRIDE, i2 = idx + 2 * STRIDE, i3 = idx + 3 * STRIDE;
        const float4 x0 = L4[i0];
        const float4 x1 = L4[i1];
        const float4 x2 = L4[i2];
        const float4 x3 = L4[i3];
        const int c0 = targets[i0 >> 4] - ((i0 & 15) << 2);
        const int c1 = targets[i1 >> 4] - ((i1 & 15) << 2);
        const int c2 = targets[i2 >> 4] - ((i2 & 15) << 2);
        const int c3 = targets[i3 >> 4] - ((i3 & 15) << 2);
        a0 += bce4(x0, c0);
        a1 += bce4(x1, c1);
        a2 += bce4(x2, c2);
        a3 += bce4(x3, c3);
    }
    for (; idx < n_vec4; idx += STRIDE) {
        a0 += bce4(L4[idx], targets[idx >> 4] - ((idx & 15) << 2));
    }

    float acc = ((a0 + a1) + (a2 + a3)) * inv_count;

    __shared__ float wave_sums[BLOCK / 64];
    const float s = block_reduce(acc, wave_sums);
    if (threadIdx.x == 0) partials[blockIdx.x] = s;   // plain store, no atomic
}

__global__ __launch_bounds__(BLOCK) void coral_loss_finish(
    const float* __restrict__ partials,
    float* __restrict__ out,
    int n_partials)
{
    float acc = 0.0f;
    for (int i = threadIdx.x; i < n_partials; i += BLOCK)
        acc += partials[i];
    __shared__ float wave_sums[BLOCK / 64];
    const float s = block_reduce(acc, wave_sums);
    if (threadIdx.x == 0) out[0] = s;
}

extern "C" void kernel_launch(void* const* d_in, const int* in_sizes, int n_in,
                              void* d_out, int out_size, void* d_ws, size_t ws_size,
                              hipStream_t stream) {
    const float* logits = (const float*)d_in[0];
    const int* targets = (const int*)d_in[1];
    float* out = (float*)d_out;
    float* partials = (float*)d_ws;

    const int n_logits = in_sizes[0];       // B * Km1
    const int n_vec4 = n_logits / 4;
    const float inv_count = 1.0f / (float)n_logits;

    coral_loss_main<<<GRID, BLOCK, 0, stream>>>(
        logits, targets, partials, n_vec4, inv_count);
    coral_loss_finish<<<1, BLOCK, 0, stream>>>(partials, out, GRID);
}

// Round 7
// 182.568 us; speedup vs baseline: 1.1374x; 1.0690x over previous
//
#include <hip/hip_runtime.h>
#include <math.h>

// CoralLossV2: mean over (B, Km1) of
//   max(x,0) - x*[t > k] + log1p(exp(-|x|))  ==  softplus(x) - x*[t > k]
// B = 524288, Km1 = 64, logits fp32, targets int32, output: 1 fp32 scalar.
//
// R5 analysis: four structurally different kernels all plateau at ~70 us
// backed-out kernel time, insensitive to load pipelining, unroll, atomics.
// Internal models (VALU ~7us, fetch ~10us, latency ~2us at 32 waves/CU)
// cannot produce 70 us. Theory: the harness's 537 MB 0xAA fill + 134 MB
// input restore leave L2/L3 full of dirty lines; our kernel's reads force
// dirty-victim writebacks and contend with the drain still queued to HBM.
// Fix attempt: nontemporal loads — read allocations are useless (inputs
// rewritten every iteration), so stop allocating on miss / forcing evictions.
// R6: compile fix — __builtin_nontemporal_load needs a native vector type,
// not HIP_vector_type<float,4>; use ext_vector_type(4).

#define BLOCK 256
#define GRID 2048
#define STRIDE (GRID * BLOCK)

typedef float floatx4 __attribute__((ext_vector_type(4)));

__device__ __forceinline__ float bce4(const floatx4 x4, const int c) {
    const float LOG2E = 1.44269504088896f;
    const float LN2   = 0.69314718055995f;
    float s = 0.0f;
    #pragma unroll
    for (int j = 0; j < 4; ++j) {
        const float x = x4[j];
        // log1p(exp(-|x|)) = ln2 * log2(1 + exp2(-|x|*log2e)) via hw trans ops
        const float e  = __builtin_amdgcn_exp2f(-fabsf(x) * LOG2E);
        const float lg = __builtin_amdgcn_logf(1.0f + e);
        // max(x,0) - x*[c > j] == (c > j) ? max(-x,0) : max(x,0)
        const float m  = fmaxf((c > j) ? -x : x, 0.0f);
        s += fmaf(LN2, lg, m);
    }
    return s;
}

__device__ __forceinline__ float block_reduce(float acc, float* wave_sums) {
    #pragma unroll
    for (int off = 32; off > 0; off >>= 1)
        acc += __shfl_down(acc, off, 64);
    const int lane = threadIdx.x & 63;
    const int wid = threadIdx.x >> 6;
    if (lane == 0) wave_sums[wid] = acc;
    __syncthreads();
    float s = 0.0f;
    if (threadIdx.x == 0) {
        #pragma unroll
        for (int w = 0; w < BLOCK / 64; ++w) s += wave_sums[w];
    }
    return s;
}

__global__ __launch_bounds__(BLOCK) void coral_loss_main(
    const float* __restrict__ logits,
    const int* __restrict__ targets,
    float* __restrict__ partials,   // GRID floats in d_ws
    int n_vec4,                     // B*Km1/4
    float inv_count)                // 1/(B*Km1)
{
    const floatx4* __restrict__ L4 = reinterpret_cast<const floatx4*>(logits);
    float a0 = 0.0f, a1 = 0.0f, a2 = 0.0f, a3 = 0.0f;
    int idx = blockIdx.x * BLOCK + threadIdx.x;

    for (; idx + 3 * STRIDE < n_vec4; idx += 4 * STRIDE) {
        const int i0 = idx, i1 = idx + STRIDE, i2 = idx + 2 * STRIDE, i3 = idx + 3 * STRIDE;
        const floatx4 x0 = __builtin_nontemporal_load(&L4[i0]);
        const floatx4 x1 = __builtin_nontemporal_load(&L4[i1]);
        const floatx4 x2 = __builtin_nontemporal_load(&L4[i2]);
        const floatx4 x3 = __builtin_nontemporal_load(&L4[i3]);
        const int c0 = __builtin_nontemporal_load(&targets[i0 >> 4]) - ((i0 & 15) << 2);
        const int c1 = __builtin_nontemporal_load(&targets[i1 >> 4]) - ((i1 & 15) << 2);
        const int c2 = __builtin_nontemporal_load(&targets[i2 >> 4]) - ((i2 & 15) << 2);
        const int c3 = __builtin_nontemporal_load(&targets[i3 >> 4]) - ((i3 & 15) << 2);
        a0 += bce4(x0, c0);
        a1 += bce4(x1, c1);
        a2 += bce4(x2, c2);
        a3 += bce4(x3, c3);
    }
    for (; idx < n_vec4; idx += STRIDE) {
        a0 += bce4(__builtin_nontemporal_load(&L4[idx]),
                   __builtin_nontemporal_load(&targets[idx >> 4]) - ((idx & 15) << 2));
    }

    float acc = ((a0 + a1) + (a2 + a3)) * inv_count;

    __shared__ float wave_sums[BLOCK / 64];
    const float s = block_reduce(acc, wave_sums);
    if (threadIdx.x == 0) partials[blockIdx.x] = s;   // plain store, no atomic
}

__global__ __launch_bounds__(BLOCK) void coral_loss_finish(
    const float* __restrict__ partials,
    float* __restrict__ out,
    int n_partials)
{
    float acc = 0.0f;
    for (int i = threadIdx.x; i < n_partials; i += BLOCK)
        acc += partials[i];
    __shared__ float wave_sums[BLOCK / 64];
    const float s = block_reduce(acc, wave_sums);
    if (threadIdx.x == 0) out[0] = s;
}

extern "C" void kernel_launch(void* const* d_in, const int* in_sizes, int n_in,
                              void* d_out, int out_size, void* d_ws, size_t ws_size,
                              hipStream_t stream) {
    const float* logits = (const float*)d_in[0];
    const int* targets = (const int*)d_in[1];
    float* out = (float*)d_out;
    float* partials = (float*)d_ws;

    const int n_logits = in_sizes[0];       // B * Km1
    const int n_vec4 = n_logits / 4;
    const float inv_count = 1.0f / (float)n_logits;

    coral_loss_main<<<GRID, BLOCK, 0, stream>>>(
        logits, targets, partials, n_vec4, inv_count);
    coral_loss_finish<<<1, BLOCK, 0, stream>>>(partials, out, GRID);
}